// Round 7
// baseline (788.775 us; speedup 1.0000x reference)
//
#include <hip/hip_runtime.h>
#include <hip/hip_bf16.h>
#include <math.h>

typedef __attribute__((ext_vector_type(8))) short s16x8;
typedef __attribute__((ext_vector_type(4))) float f32x4;

#define T_TOK 16384
#define D_DIM 1024
#define F_DIM 2048
#define E_NUM 8
#define RCAP 34816  // 2*T + 8*256 worst-case 256-padded rows
#define MAXTH 17    // tile-row groups of 8 (covers 136 tiles)

__device__ __forceinline__ unsigned short f2b(float f) {
  unsigned u = __float_as_uint(f);
  u += 0x7fff + ((u >> 16) & 1);
  return (unsigned short)(u >> 16);
}
__device__ __forceinline__ unsigned pk2(float a, float b) {
  __hip_bfloat162 h = __float22bfloat162_rn(make_float2(a, b));
  return *reinterpret_cast<unsigned*>(&h);
}
__device__ __forceinline__ void gload16(const void* g, void* l) {
  __builtin_amdgcn_global_load_lds(
      (const __attribute__((address_space(1))) unsigned*)g,
      (__attribute__((address_space(3))) unsigned*)l, 16, 0, 0);
}

// ---------------- weight cast fp32 -> bf16 ----------------
__global__ void castw_k(const float* __restrict__ w1, const float* __restrict__ w2,
                        unsigned short* __restrict__ w1b, unsigned short* __restrict__ w2b) {
  size_t i = ((size_t)blockIdx.x * 256 + threadIdx.x) * 4;
  float4 a = *(const float4*)(w1 + i);
  float4 b = *(const float4*)(w2 + i);
  uint2 ua, ub;
  ua.x = pk2(a.x, a.y); ua.y = pk2(a.z, a.w);
  ub.x = pk2(b.x, b.y); ub.y = pk2(b.z, b.w);
  *(uint2*)(w1b + i) = ua;
  *(uint2*)(w2b + i) = ub;
}

// ---------------- router (+ fused x->bf16 cast) ----------------
__global__ void router_k(const float* __restrict__ x, const float* __restrict__ wr,
                         int* __restrict__ topi, float* __restrict__ topw,
                         float* __restrict__ probs8, unsigned short* __restrict__ xb) {
  int tid = threadIdx.x, wid = tid >> 6, lane = tid & 63;
  int t = blockIdx.x * 4 + wid;
  const float* xr = x + (size_t)t * D_DIM;
  float4 xv[4];
#pragma unroll
  for (int i = 0; i < 4; ++i) xv[i] = *(const float4*)(xr + i * 256 + lane * 4);
#pragma unroll
  for (int i = 0; i < 4; ++i) {
    uint2 u; u.x = pk2(xv[i].x, xv[i].y); u.y = pk2(xv[i].z, xv[i].w);
    *(uint2*)(xb + (size_t)t * D_DIM + i * 256 + lane * 4) = u;
  }
  float logit[E_NUM];
#pragma unroll
  for (int e = 0; e < E_NUM; ++e) {
    const float* wrow = wr + e * D_DIM;
    float p = 0.f;
#pragma unroll
    for (int i = 0; i < 4; ++i) {
      float4 wv = *(const float4*)(wrow + i * 256 + lane * 4);
      p += xv[i].x * wv.x + xv[i].y * wv.y + xv[i].z * wv.z + xv[i].w * wv.w;
    }
    for (int s = 32; s; s >>= 1) p += __shfl_xor(p, s);
    logit[e] = p;
  }
  if (lane == 0) {
    float m = logit[0];
    for (int e = 1; e < E_NUM; ++e) m = fmaxf(m, logit[e]);
    float pr[E_NUM];
    float sum = 0.f;
    for (int e = 0; e < E_NUM; ++e) { pr[e] = expf(logit[e] - m); sum += pr[e]; }
    float inv = 1.f / sum;
    for (int e = 0; e < E_NUM; ++e) { pr[e] *= inv; probs8[t * 8 + e] = pr[e]; }
    int i0 = 0;
    for (int e = 1; e < E_NUM; ++e) if (pr[e] > pr[i0]) i0 = e;
    int i1 = (i0 == 0) ? 1 : 0;
    for (int e = 0; e < E_NUM; ++e) if (e != i0 && pr[e] > pr[i1]) i1 = e;
    float wsum = pr[i0] + pr[i1];
    topi[2 * t] = i0;  topi[2 * t + 1] = i1;
    topw[2 * t] = pr[i0] / wsum;  topw[2 * t + 1] = pr[i1] / wsum;
  }
}

// ---------------- histogram ----------------
__global__ void hist_k(const int* __restrict__ topi, const float* __restrict__ probs8,
                       int* __restrict__ cnt, float* __restrict__ usage) {
  __shared__ int sc[E_NUM];
  __shared__ float su[E_NUM];
  int tid = threadIdx.x;
  if (tid < E_NUM) { sc[tid] = 0; su[tid] = 0.f; }
  __syncthreads();
  for (int i = blockIdx.x * 256 + tid; i < 2 * T_TOK; i += 256 * 64)
    atomicAdd(&sc[topi[i]], 1);
  for (int i = blockIdx.x * 256 + tid; i < 8 * T_TOK; i += 256 * 64)
    atomicAdd(&su[i & 7], probs8[i]);
  __syncthreads();
  if (tid < E_NUM) { atomicAdd(&cnt[tid], sc[tid]); atomicAdd(&usage[tid], su[tid]); }
}

// ---------------- offsets (256-padded) + tile table + aux ----------------
__global__ void scan_k(const int* __restrict__ cnt, int* __restrict__ offs,
                       int* __restrict__ tl_e, int* __restrict__ tl_rb, int* __restrict__ tlcnt,
                       const float* __restrict__ usage, float* __restrict__ aux) {
  if (threadIdx.x == 0 && blockIdx.x == 0) {
    int o = 0, n = 0;
    for (int e = 0; e < E_NUM; ++e) {
      offs[e] = o;
      int pe = (cnt[e] + 255) & ~255;
      for (int r = 0; r < pe; r += 256) { tl_e[n] = e; tl_rb[n] = o + r; ++n; }
      o += pe;
    }
    offs[E_NUM] = o;
    *tlcnt = n;
    float s = 0.f;
    for (int e = 0; e < E_NUM; ++e) { float m = usage[e] * (1.f / T_TOK); s += m * m; }
    *aux = (float)E_NUM * s;
  }
}

// ---------------- assignment: pair -> row ----------------
__global__ void assign_k(const int* __restrict__ topi, const int* __restrict__ offs,
                         int* __restrict__ cur, int* __restrict__ rowpair) {
  int p = blockIdx.x * 256 + threadIdx.x;
  int lane = threadIdx.x & 63;
  int e = topi[p];
  int r = 0;
#pragma unroll
  for (int ee = 0; ee < E_NUM; ++ee) {
    unsigned long long mask = __ballot(e == ee);
    if (e == ee) {
      int leader = __ffsll((unsigned long long)mask) - 1;
      int rank = __popcll(mask & ((1ull << lane) - 1ull));
      int b = 0;
      if (lane == leader) b = atomicAdd(&cur[ee], (int)__popcll(mask));
      b = __shfl(b, leader);
      r = offs[ee] + b + rank;
    }
  }
  rowpair[r] = p;
}

// ====== triple-buffered counted-vmcnt GEMM body (BM=256,BN=128,BK=64) ======
// Per K-tile: 1 barrier, vmcnt(6) (never 0 until the last tile); stage tile
// t+2 while computing t. 8 waves (2M x 4N), wave tile 128x32, acc[8][2].

#define GEMM_BODY(NT, LDB, STAGE_A_SRC, EPILOGUE)                              \
  int tid = threadIdx.x, wid = tid >> 6, lane = tid & 63;                      \
  int wm = wid >> 2, wn = wid & 3;                                             \
  int l8 = lane >> 3, j7 = lane & 7;                                           \
  int sg = ((j7 ^ l8) << 3);                                                   \
  int rl = lane & 15, g4 = lane >> 4;                                          \
  f32x4 acc[8][2] = {};                                                        \
  /* prologue: stage tiles 0,1 */                                              \
  _Pragma("unroll") for (int i = 0; i < 4; ++i)                                \
      gload16(STAGE_A_SRC(i, 0), &Asl[0][(i * 64 + wid * 8) * 64]);            \
  _Pragma("unroll") for (int i = 0; i < 2; ++i)                                \
      gload16(Bg + (size_t)(i * 64) * LDB + 0, &Bsl[0][(i * 64 + wid * 8) * 64]);\
  _Pragma("unroll") for (int i = 0; i < 4; ++i)                                \
      gload16(STAGE_A_SRC(i, 64), &Asl[1][(i * 64 + wid * 8) * 64]);           \
  _Pragma("unroll") for (int i = 0; i < 2; ++i)                                \
      gload16(Bg + (size_t)(i * 64) * LDB + 64, &Bsl[1][(i * 64 + wid * 8) * 64]);\
  _Pragma("unroll")                                                            \
  for (int t = 0; t < NT; ++t) {                                               \
    if (t < NT - 1) asm volatile("s_waitcnt vmcnt(6)" ::: "memory");           \
    else            asm volatile("s_waitcnt vmcnt(0)" ::: "memory");           \
    __builtin_amdgcn_sched_barrier(0);                                         \
    __builtin_amdgcn_s_barrier();                                              \
    __builtin_amdgcn_sched_barrier(0);                                         \
    const int cur = t % 3, pf = (t + 2) % 3;                                   \
    const int kpf = (t + 2) * 64;                                              \
    const short* As = Asl[cur];                                                \
    const short* Bs = Bsl[cur];                                                \
    const bool dopf = t < NT - 2;                                              \
    _Pragma("unroll")                                                          \
    for (int kh = 0; kh < 2; ++kh) {                                           \
      if (dopf) {                                                              \
        if (kh == 0) {                                                         \
          gload16(STAGE_A_SRC(0, kpf), &Asl[pf][(0 * 64 + wid * 8) * 64]);     \
          gload16(STAGE_A_SRC(1, kpf), &Asl[pf][(1 * 64 + wid * 8) * 64]);     \
          gload16(STAGE_A_SRC(2, kpf), &Asl[pf][(2 * 64 + wid * 8) * 64]);     \
        } else {                                                               \
          gload16(STAGE_A_SRC(3, kpf), &Asl[pf][(3 * 64 + wid * 8) * 64]);     \
          gload16(Bg + (size_t)0 * LDB + kpf, &Bsl[pf][(0 * 64 + wid * 8) * 64]);\
          gload16(Bg + (size_t)64 * LDB + kpf, &Bsl[pf][(1 * 64 + wid * 8) * 64]);\
        }                                                                      \
      }                                                                        \
      int gr = (((kh * 4 + g4) ^ j7) << 3);                                    \
      s16x8 av[8], bv[2];                                                      \
      _Pragma("unroll") for (int mm = 0; mm < 8; ++mm)                         \
          av[mm] = *(const s16x8*)&As[(wm * 128 + mm * 16 + rl) * 64 + gr];    \
      _Pragma("unroll") for (int nn = 0; nn < 2; ++nn)                         \
          bv[nn] = *(const s16x8*)&Bs[(wn * 32 + nn * 16 + rl) * 64 + gr];     \
      __builtin_amdgcn_s_setprio(1);                                           \
      _Pragma("unroll") for (int mm = 0; mm < 8; ++mm)                         \
        _Pragma("unroll") for (int nn = 0; nn < 2; ++nn)                       \
          acc[mm][nn] = __builtin_amdgcn_mfma_f32_16x16x32_bf16(               \
              av[mm], bv[nn], acc[mm][nn], 0, 0, 0);                           \
      __builtin_amdgcn_s_setprio(0);                                           \
    }                                                                          \
  }                                                                            \
  EPILOGUE

// ---------------- GEMM1: hseg = gelu(gather(xb) @ w1[e]^T) ----------------
__global__ __launch_bounds__(512, 1) void gemm1t_k(
    const unsigned short* __restrict__ xb, const unsigned short* __restrict__ w1b,
    const int* __restrict__ tl_e, const int* __restrict__ tl_rb, const int* __restrict__ tlcnt,
    const int* __restrict__ rowpair, const unsigned short* __restrict__ zrow,
    unsigned short* __restrict__ hseg, int segbase, int segrows) {
  int d = blockIdx.x;
  int tile = (d & 7) + 8 * (d >> 7);   // 16 nt-siblings share d&7 -> same XCD
  int nt = (d >> 3) & 15;
  if (tile >= *tlcnt) return;
  int e = tl_e[tile], rowbase = tl_rb[tile];
  if (rowbase < segbase || rowbase >= segbase + segrows) return;

  __shared__ short Asl[3][256 * 64];
  __shared__ short Bsl[3][128 * 64];
  {
    int wid_ = threadIdx.x >> 6, l8_ = (threadIdx.x & 63) >> 3, j7_ = threadIdx.x & 7;
    int sg_ = ((j7_ ^ l8_) << 3);
    const unsigned short* abase[4];
#pragma unroll
    for (int i = 0; i < 4; ++i) {
      int p = rowpair[rowbase + i * 64 + wid_ * 8 + l8_];
      abase[i] = (p >= 0) ? (xb + (size_t)(p >> 1) * D_DIM) : zrow;
    }
    const unsigned short* Bg =
        w1b + ((size_t)e * F_DIM + nt * 128) * D_DIM + (size_t)(wid_ * 8 + l8_) * D_DIM + sg_;
#define A1SRC(i, k0) (abase[i] + (k0) + sg_)
    GEMM_BODY(16, D_DIM, A1SRC, {
      size_t rloc = (size_t)(rowbase - segbase);
      int c0 = nt * 128 + wn * 32 + rl;
      _Pragma("unroll") for (int mm = 0; mm < 8; ++mm)
        _Pragma("unroll") for (int j = 0; j < 4; ++j) {
          size_t rr = (rloc + wm * 128 + mm * 16 + g4 * 4 + j) * F_DIM;
          _Pragma("unroll") for (int nn = 0; nn < 2; ++nn) {
            float v = acc[mm][nn][j];
            float g = 0.5f * v * (1.f + erff(v * 0.70710678118f));
            hseg[rr + c0 + nn * 16] = f2b(g);
          }
        }
    })
#undef A1SRC
  }
}

// ---------------- GEMM2: out[t] += w * (hseg @ w2[e]^T), atomic scatter ----------------
__global__ __launch_bounds__(512, 1) void gemm2t_k(
    const unsigned short* __restrict__ hseg, const unsigned short* __restrict__ w2b,
    const int* __restrict__ tl_e, const int* __restrict__ tl_rb, const int* __restrict__ tlcnt,
    const int* __restrict__ rowpair, const float* __restrict__ topw,
    float* __restrict__ out, int segbase, int segrows) {
  int d = blockIdx.x;
  int tile = (d & 7) + 8 * (d >> 6);   // 8 nt-siblings share d&7 -> same XCD
  int nt = (d >> 3) & 7;
  if (tile >= *tlcnt) return;
  int e = tl_e[tile], rowbase = tl_rb[tile];
  if (rowbase < segbase || rowbase >= segbase + segrows) return;

  __shared__ short Asl[3][256 * 64];
  __shared__ short Bsl[3][128 * 64];
  {
    int wid_ = threadIdx.x >> 6, l8_ = (threadIdx.x & 63) >> 3, j7_ = threadIdx.x & 7;
    int sg_ = ((j7_ ^ l8_) << 3);
    const unsigned short* Ag =
        hseg + (size_t)(rowbase - segbase) * F_DIM + (size_t)(wid_ * 8 + l8_) * F_DIM + sg_;
    const unsigned short* Bg =
        w2b + ((size_t)e * D_DIM + nt * 128) * F_DIM + (size_t)(wid_ * 8 + l8_) * F_DIM + sg_;
#define A2SRC(i, k0) (Ag + (size_t)((i) * 64) * F_DIM + (k0))
    GEMM_BODY(32, F_DIM, A2SRC, {
      _Pragma("unroll") for (int mm = 0; mm < 8; ++mm)
        _Pragma("unroll") for (int j = 0; j < 4; ++j) {
          int lr = wm * 128 + mm * 16 + g4 * 4 + j;
          int p = rowpair[rowbase + lr];
          if (p >= 0) {
            float wgt = topw[p];
            float* op = out + (size_t)(p >> 1) * D_DIM + nt * 128 + wn * 32 + rl;
            _Pragma("unroll") for (int nn = 0; nn < 2; ++nn)
              unsafeAtomicAdd(op + nn * 16, wgt * acc[mm][nn][j]);
          }
        }
    })
#undef A2SRC
  }
}

extern "C" void kernel_launch(void* const* d_in, const int* in_sizes, int n_in,
                              void* d_out, int out_size, void* d_ws, size_t ws_size,
                              hipStream_t stream) {
  const float* x  = (const float*)d_in[0];
  const float* wr = (const float*)d_in[1];
  const float* w1 = (const float*)d_in[2];
  const float* w2 = (const float*)d_in[3];
  float* out = (float*)d_out;

  char* ws = (char*)d_ws;
  int* cnt   = (int*)ws;         // [8]
  int* cur   = cnt + 8;          // [8]
  int* offs  = cnt + 16;         // [9]
  int* tlcnt = cnt + 25;         // [1]
  int* tl_e  = cnt + 26;         // [136]
  int* tl_rb = cnt + 162;        // [136]
  float* usage = (float*)(cnt + 298);  // [8]
  unsigned short* zrow = (unsigned short*)(ws + 4096);  // 2KB zeros
  size_t off = 8192;
  int*   topi = (int*)(ws + off);     off += (size_t)2 * T_TOK * 4;
  float* topw = (float*)(ws + off);   off += (size_t)2 * T_TOK * 4;
  int*   rowpair = (int*)(ws + off);  off += (size_t)RCAP * 4;
  float* probs8 = (float*)(ws + off); off += (size_t)T_TOK * 8 * 4;
  off = (off + 255) & ~(size_t)255;

  unsigned short* xb = (unsigned short*)(ws + off);
  off += (size_t)T_TOK * D_DIM * 2;                       // 33.6 MB
  unsigned short* w1b = (unsigned short*)(ws + off);
  off += (size_t)E_NUM * F_DIM * D_DIM * 2;               // 33.6 MB
  unsigned short* w2b = (unsigned short*)(ws + off);
  off += (size_t)E_NUM * F_DIM * D_DIM * 2;               // 33.6 MB
  if (ws_size < off + (size_t)4096 * F_DIM * 2) return;   // need >= 16.8MB hseg
  size_t avail = ws_size - off;
  size_t segcap = (avail / ((size_t)F_DIM * 2)) & ~(size_t)255;
  int segrows = segcap > (size_t)RCAP ? RCAP : (int)segcap;
  unsigned short* hseg = (unsigned short*)(ws + off);
  int nseg = (RCAP + segrows - 1) / segrows;

  hipMemsetAsync(ws, 0, 8192, stream);
  hipMemsetAsync(rowpair, 0xFF, (size_t)RCAP * 4, stream);
  hipMemsetAsync(d_out, 0, (size_t)out_size * 4, stream);
  castw_k<<<16384, 256, 0, stream>>>(w1, w2, w1b, w2b);
  router_k<<<T_TOK / 4, 256, 0, stream>>>(x, wr, topi, topw, probs8, xb);
  hist_k<<<64, 256, 0, stream>>>(topi, probs8, cnt, usage);
  scan_k<<<1, 64, 0, stream>>>(cnt, offs, tl_e, tl_rb, tlcnt, usage, out + (size_t)T_TOK * D_DIM);
  assign_k<<<2 * T_TOK / 256, 256, 0, stream>>>(topi, offs, cur, rowpair);

  for (int s = 0; s < nseg; ++s) {
    int segbase = s * segrows;
    gemm1t_k<<<8 * 16 * MAXTH, 512, 0, stream>>>(xb, w1b, tl_e, tl_rb, tlcnt, rowpair, zrow,
                                                 hseg, segbase, segrows);
    gemm2t_k<<<8 * 8 * MAXTH, 512, 0, stream>>>(hseg, w2b, tl_e, tl_rb, tlcnt, rowpair, topw,
                                                out, segbase, segrows);
  }
}